// Round 14
// baseline (135.006 us; speedup 1.0000x reference)
//
#include <hip/hip_runtime.h>
#include <hip/hip_fp16.h>

#define D_FEAT 64
#define NPB 128            // nodes per bucket (node >> 7)
#define NBMAX 1024         // bucket count both sides (pow2)
#define CHUNK 8192         // edges per partition block (arrA run = 8 ints = 32B)
#define EPT 32             // CHUNK / 256
#define CAPB 2816          // full-bucket register staging capacity
#define CAPB_H 1536        // half-bucket srcS capacity (mean 1023 + ~16 sigma)
#define RPT 6              // ceil(CAPB / 512)

// ---------------- zero ----------------
__global__ void zero_ints(int* __restrict__ p, int n) {
    int i = blockIdx.x * blockDim.x + threadIdx.x;
    int stride = gridDim.x * blockDim.x;
    for (int j = i; j < n; j += stride) p[j] = 0;
}

// exclusive scan over 256 threads via wave shuffles (2 barriers)
__device__ __forceinline__ int excl_scan_256(int v, int* wsum4) {
    int lane = threadIdx.x & 63, w = threadIdx.x >> 6;
    int inc = v;
    #pragma unroll
    for (int off = 1; off < 64; off <<= 1) {
        int y = __shfl_up(inc, off);
        if (lane >= off) inc += y;
    }
    if (lane == 63) wsum4[w] = inc;
    __syncthreads();
    int add = 0;
    #pragma unroll
    for (int i = 0; i < 3; ++i) if (i < w) add += wsum4[i];
    int r = add + inc - v;
    __syncthreads();
    return r;
}

// ---------------- bucket counts for BOTH sides ----------------
__global__ __launch_bounds__(256) void bcnt_kernel(
        const int* __restrict__ src, const int* __restrict__ dst, int n_edges,
        int* __restrict__ dbcnt8, int* __restrict__ sbcnt8) {
    __shared__ int ld[NBMAX];
    __shared__ int ls[NBMAX];
    int t = threadIdx.x;
    for (int i = t; i < NBMAX; i += 256) { ld[i] = 0; ls[i] = 0; }
    __syncthreads();
    int i0 = blockIdx.x * blockDim.x + t;
    int stride = gridDim.x * blockDim.x;
    for (int e = i0; e < n_edges; e += stride) {
        atomicAdd(&ld[dst[e] >> 7], 1);
        atomicAdd(&ls[src[e] >> 7], 1);
    }
    __syncthreads();
    int* dmy = dbcnt8 + (blockIdx.x & 7) * NBMAX;
    int* smy = sbcnt8 + (blockIdx.x & 7) * NBMAX;
    for (int i = t; i < NBMAX; i += 256) {
        if (ld[i]) atomicAdd(&dmy[i], ld[i]);
        if (ls[i]) atomicAdd(&smy[i], ls[i]);
    }
}

// ---------------- dual exclusive scan: block 0 = dst side, block 1 = src side ----
__global__ void scan2_kernel(const int* __restrict__ dbcnt8, const int* __restrict__ sbcnt8,
                             int* __restrict__ dbstart, int* __restrict__ gcursor,
                             int* __restrict__ sbstart, int* __restrict__ scursor,
                             int n_edges) {
    __shared__ int wsum[16];
    int t = threadIdx.x, lane = t & 63, w = t >> 6;
    const int* c8 = (blockIdx.x == 0) ? dbcnt8 : sbcnt8;
    int* bs = (blockIdx.x == 0) ? dbstart : sbstart;
    int* cur = (blockIdx.x == 0) ? gcursor : scursor;
    int v = 0;
    #pragma unroll
    for (int c = 0; c < 8; ++c) v += c8[c * NBMAX + t];
    int inc = v;
    #pragma unroll
    for (int off = 1; off < 64; off <<= 1) {
        int y = __shfl_up(inc, off);
        if (lane >= off) inc += y;
    }
    if (lane == 63) wsum[w] = inc;
    __syncthreads();
    int add = 0;
    #pragma unroll
    for (int i = 0; i < 15; ++i) if (i < w) add += wsum[i];
    int ex = add + inc - v;
    bs[t] = ex;
    cur[t] = ex;
    if (t == NBMAX - 1) bs[NBMAX] = n_edges;
}

// ---------------- fused dual partition (CHUNK=8192, wave-shuffle scans) ----------
// Phase D: arrA[pk = (src<<7)|(dst&127)] bucketed by dst>>7
// Phase S: arrS[src&127 byte] bucketed by src>>7  (same LDS reused)
__global__ __launch_bounds__(256) void dualpart_kernel(
        const int* __restrict__ src, const int* __restrict__ dst, int n_edges,
        int* __restrict__ gcursor, int* __restrict__ scursor,
        int* __restrict__ arrA, unsigned char* __restrict__ arrS) {
    __shared__ int lhist[NBMAX];
    __shared__ int ldelta[NBMAX];
    __shared__ int lcur[NBMAX];
    __shared__ int wsum4[4];
    __shared__ int pkLDS[CHUNK];
    __shared__ unsigned short bktLDS[CHUNK];

    int t = threadIdx.x;
    long long cbase = (long long)blockIdx.x * CHUNK;
    int cnt = (n_edges - cbase < CHUNK) ? (int)(n_edges - cbase) : CHUNK;

    for (int i = t; i < NBMAX; i += 256) lhist[i] = 0;
    __syncthreads();

    int ssrc[EPT], sdst[EPT];
    #pragma unroll
    for (int i = 0; i < EPT; ++i) {
        long long e = cbase + t + i * 256;
        if (e < n_edges) {
            ssrc[i] = src[e];
            sdst[i] = dst[e];
            atomicAdd(&lhist[sdst[i] >> 7], 1);
        } else {
            ssrc[i] = -1;
            sdst[i] = -1;
        }
    }
    __syncthreads();

    // ---- phase D scan (wave shuffle) ----
    int b0 = 4 * t;
    int h0 = lhist[b0], h1 = lhist[b0 + 1], h2v = lhist[b0 + 2], h3 = lhist[b0 + 3];
    int tot = h0 + h1 + h2v + h3;
    int ex = excl_scan_256(tot, wsum4);
    int ls0 = ex, ls1 = ex + h0, ls2 = ex + h0 + h1, ls3 = ex + h0 + h1 + h2v;
    lcur[b0] = ls0; lcur[b0 + 1] = ls1; lcur[b0 + 2] = ls2; lcur[b0 + 3] = ls3;
    if (h0) ldelta[b0] = atomicAdd(&gcursor[b0], h0) - ls0;
    if (h1) ldelta[b0 + 1] = atomicAdd(&gcursor[b0 + 1], h1) - ls1;
    if (h2v) ldelta[b0 + 2] = atomicAdd(&gcursor[b0 + 2], h2v) - ls2;
    if (h3) ldelta[b0 + 3] = atomicAdd(&gcursor[b0 + 3], h3) - ls3;
    __syncthreads();
    #pragma unroll
    for (int i = 0; i < EPT; ++i) {
        if (sdst[i] >= 0) {
            int b = sdst[i] >> 7;
            int slot = atomicAdd(&lcur[b], 1);
            pkLDS[slot] = (ssrc[i] << 7) | (sdst[i] & 127);
            bktLDS[slot] = (unsigned short)b;
        }
    }
    __syncthreads();
    for (int j = t; j < cnt; j += 256) {
        int b = bktLDS[j];
        arrA[j + ldelta[b]] = pkLDS[j];
    }
    __syncthreads();

    // ---- phase S (reuse all LDS) ----
    for (int i = t; i < NBMAX; i += 256) lhist[i] = 0;
    __syncthreads();
    #pragma unroll
    for (int i = 0; i < EPT; ++i) {
        if (ssrc[i] >= 0) atomicAdd(&lhist[ssrc[i] >> 7], 1);
    }
    __syncthreads();
    h0 = lhist[b0]; h1 = lhist[b0 + 1]; h2v = lhist[b0 + 2]; h3 = lhist[b0 + 3];
    tot = h0 + h1 + h2v + h3;
    ex = excl_scan_256(tot, wsum4);
    ls0 = ex; ls1 = ex + h0; ls2 = ex + h0 + h1; ls3 = ex + h0 + h1 + h2v;
    lcur[b0] = ls0; lcur[b0 + 1] = ls1; lcur[b0 + 2] = ls2; lcur[b0 + 3] = ls3;
    if (h0) ldelta[b0] = atomicAdd(&scursor[b0], h0) - ls0;
    if (h1) ldelta[b0 + 1] = atomicAdd(&scursor[b0 + 1], h1) - ls1;
    if (h2v) ldelta[b0 + 2] = atomicAdd(&scursor[b0 + 2], h2v) - ls2;
    if (h3) ldelta[b0 + 3] = atomicAdd(&scursor[b0 + 3], h3) - ls3;
    __syncthreads();
    unsigned char* stg = (unsigned char*)pkLDS;
    #pragma unroll
    for (int i = 0; i < EPT; ++i) {
        if (ssrc[i] >= 0) {
            int b = ssrc[i] >> 7;
            int slot = atomicAdd(&lcur[b], 1);
            stg[slot] = (unsigned char)(ssrc[i] & 127);
            bktLDS[slot] = (unsigned short)b;
        }
    }
    __syncthreads();
    for (int j = t; j < cnt; j += 256) {
        int b = bktLDS[j];
        arrS[j + ldelta[b]] = stg[j];
    }
}

// ---------------- out-degree -> oscale (one block per src bucket, race-free) ------
__global__ __launch_bounds__(256) void scount_kernel(
        const unsigned char* __restrict__ arrS, const int* __restrict__ sbstart,
        float* __restrict__ oscale, int n_nodes) {
    __shared__ int lh[NPB];
    int b = blockIdx.x, t = threadIdx.x;
    int s = sbstart[b], e = sbstart[b + 1];
    if (t < NPB) lh[t] = 0;
    __syncthreads();
    for (int i = s + t; i < e; i += 256) atomicAdd(&lh[arrS[i]], 1);
    __syncthreads();
    if (t < NPB) {
        int node = b * NPB + t;
        if (node < n_nodes) {
            int od = lh[t];
            oscale[node] = rsqrtf((float)(od > 1 ? od : 1));
        }
    }
}

// ---------------- h prepass (grid-stride; h2 overwrites arrS only after scount) ---
__global__ void h_prepass_kernel(const float4* __restrict__ emb4,
                                 const float* __restrict__ oscale,
                                 uint2* __restrict__ h2, int n_total, int n_nodes) {
    int i = blockIdx.x * blockDim.x + threadIdx.x;
    int stride = gridDim.x * blockDim.x;
    for (int j = i; j < n_total; j += stride) {
        int node = j >> 4;
        uint2 r;
        if (node < n_nodes) {
            float s = oscale[node];
            float4 v = emb4[j];
            __half2 a = __floats2half2_rn(v.x * s, v.y * s);
            __half2 b = __floats2half2_rn(v.z * s, v.w * s);
            union { __half2 h; unsigned int u; } ua, ub;
            ua.h = a; ub.h = b;
            r.x = ua.u; r.y = ub.u;
        } else {
            r.x = 0; r.y = 0;
        }
        h2[j] = r;
    }
}

// ---------------- fused sort + aggregate: 2-node interleaved gathers ----------
__global__ __launch_bounds__(512) void sortagg_kernel(
        const uint2* __restrict__ h2, const int* __restrict__ arrA,
        const int* __restrict__ dbstart, float* __restrict__ out, int n_nodes) {
    __shared__ int lh[64];
    __shared__ int lst[64];
    __shared__ int lcur[64];
    __shared__ int srcS[CAPB_H];
    int b = blockIdx.x >> 1, half = blockIdx.x & 1;
    int t = threadIdx.x;
    int s = dbstart[b], e = dbstart[b + 1];
    int cnt = e - s;
    bool fit = (cnt <= CAPB);

    if (t < 64) lh[t] = 0;
    __syncthreads();
    int pkreg[RPT];
    if (fit) {
        #pragma unroll
        for (int i = 0; i < RPT; ++i) {
            int idx = t + i * 512;
            int pk = (idx < cnt) ? arrA[s + idx] : -1;
            pkreg[i] = pk;
            if (pk >= 0 && (((pk >> 6) & 1) == half)) atomicAdd(&lh[pk & 63], 1);
        }
    } else {
        for (int i = t; i < cnt; i += 512) {
            int v = arrA[s + i];
            if (((v >> 6) & 1) == half) atomicAdd(&lh[v & 63], 1);
        }
    }
    __syncthreads();
    if (t < 64) {
        int l0 = lh[t];
        int a = l0;
        #pragma unroll
        for (int off = 1; off < 64; off <<= 1) {
            int y = __shfl_up(a, off);
            if (t >= off) a += y;
        }
        lst[t] = a - l0;
        lcur[t] = a - l0;
    }
    __syncthreads();
    int halfcnt = lst[63] + lh[63];
    bool useS = fit && (halfcnt <= CAPB_H);
    if (useS) {
        #pragma unroll
        for (int i = 0; i < RPT; ++i) {
            int pk = pkreg[i];
            if (pk >= 0 && (((pk >> 6) & 1) == half)) {
                int slot = atomicAdd(&lcur[pk & 63], 1);
                srcS[slot] = pk >> 7;
            }
        }
    }
    __syncthreads();

    int w = t >> 6, L = t & 63, g = L >> 4, c = L & 15;
    int nbase = b * NPB + half * 64;
    union { unsigned int u; __half2 h; } uc;

    if (useS) {
        // process node pairs: 8 gathers in flight per lane
        for (int p = 0; p < 8; p += 2) {
            int nl0 = w * 8 + p, nl1 = nl0 + 1;
            int node0 = nbase + nl0, node1 = nbase + nl1;
            bool v0 = node0 < n_nodes, v1 = node1 < n_nodes;
            int st0 = lst[nl0], deg0 = v0 ? lh[nl0] : 0, en0 = st0 + deg0;
            int st1 = lst[nl1], deg1 = v1 ? lh[nl1] : 0, en1 = st1 + deg1;
            float a0x = 0.f, a0y = 0.f, a0z = 0.f, a0w = 0.f;
            float a1x = 0.f, a1y = 0.f, a1z = 0.f, a1w = 0.f;
            int it0 = (deg0 + 15) >> 4, it1 = (deg1 + 15) >> 4;
            int iters = it0 > it1 ? it0 : it1;
            int i0 = st0 + g, i1 = st1 + g;
            for (int it = 0; it < iters; ++it) {
                int ea0 = i0, eb0 = i0 + 4, ec0 = i0 + 8, ed0 = i0 + 12;
                int ea1 = i1, eb1 = i1 + 4, ec1 = i1 + 8, ed1 = i1 + 12;
                int sa0 = (ea0 < en0) ? srcS[ea0] : n_nodes;
                int sb0 = (eb0 < en0) ? srcS[eb0] : n_nodes;
                int sc0 = (ec0 < en0) ? srcS[ec0] : n_nodes;
                int sd0 = (ed0 < en0) ? srcS[ed0] : n_nodes;
                int sa1 = (ea1 < en1) ? srcS[ea1] : n_nodes;
                int sb1 = (eb1 < en1) ? srcS[eb1] : n_nodes;
                int sc1 = (ec1 < en1) ? srcS[ec1] : n_nodes;
                int sd1 = (ed1 < en1) ? srcS[ed1] : n_nodes;
                uint2 va0 = h2[(size_t)sa0 * 16 + c];
                uint2 vb0 = h2[(size_t)sb0 * 16 + c];
                uint2 vc0 = h2[(size_t)sc0 * 16 + c];
                uint2 vd0 = h2[(size_t)sd0 * 16 + c];
                uint2 va1 = h2[(size_t)sa1 * 16 + c];
                uint2 vb1 = h2[(size_t)sb1 * 16 + c];
                uint2 vc1 = h2[(size_t)sc1 * 16 + c];
                uint2 vd1 = h2[(size_t)sd1 * 16 + c];
                float2 f;
                uc.u = va0.x; f = __half22float2(uc.h); a0x += f.x; a0y += f.y;
                uc.u = va0.y; f = __half22float2(uc.h); a0z += f.x; a0w += f.y;
                uc.u = vb0.x; f = __half22float2(uc.h); a0x += f.x; a0y += f.y;
                uc.u = vb0.y; f = __half22float2(uc.h); a0z += f.x; a0w += f.y;
                uc.u = vc0.x; f = __half22float2(uc.h); a0x += f.x; a0y += f.y;
                uc.u = vc0.y; f = __half22float2(uc.h); a0z += f.x; a0w += f.y;
                uc.u = vd0.x; f = __half22float2(uc.h); a0x += f.x; a0y += f.y;
                uc.u = vd0.y; f = __half22float2(uc.h); a0z += f.x; a0w += f.y;
                uc.u = va1.x; f = __half22float2(uc.h); a1x += f.x; a1y += f.y;
                uc.u = va1.y; f = __half22float2(uc.h); a1z += f.x; a1w += f.y;
                uc.u = vb1.x; f = __half22float2(uc.h); a1x += f.x; a1y += f.y;
                uc.u = vb1.y; f = __half22float2(uc.h); a1z += f.x; a1w += f.y;
                uc.u = vc1.x; f = __half22float2(uc.h); a1x += f.x; a1y += f.y;
                uc.u = vc1.y; f = __half22float2(uc.h); a1z += f.x; a1w += f.y;
                uc.u = vd1.x; f = __half22float2(uc.h); a1x += f.x; a1y += f.y;
                uc.u = vd1.y; f = __half22float2(uc.h); a1z += f.x; a1w += f.y;
                i0 += 16; i1 += 16;
            }
            a0x += __shfl_xor(a0x, 16); a0y += __shfl_xor(a0y, 16);
            a0z += __shfl_xor(a0z, 16); a0w += __shfl_xor(a0w, 16);
            a0x += __shfl_xor(a0x, 32); a0y += __shfl_xor(a0y, 32);
            a0z += __shfl_xor(a0z, 32); a0w += __shfl_xor(a0w, 32);
            a1x += __shfl_xor(a1x, 16); a1y += __shfl_xor(a1y, 16);
            a1z += __shfl_xor(a1z, 16); a1w += __shfl_xor(a1w, 16);
            a1x += __shfl_xor(a1x, 32); a1y += __shfl_xor(a1y, 32);
            a1z += __shfl_xor(a1z, 32); a1w += __shfl_xor(a1w, 32);
            if (g == 0) {
                if (v0) {
                    float is = rsqrtf((float)(deg0 > 1 ? deg0 : 1));
                    float4 r;
                    r.x = a0x * is; r.y = a0y * is; r.z = a0z * is; r.w = a0w * is;
                    ((float4*)out)[(size_t)node0 * 16 + c] = r;
                }
                if (v1) {
                    float is = rsqrtf((float)(deg1 > 1 ? deg1 : 1));
                    float4 r;
                    r.x = a1x * is; r.y = a1y * is; r.z = a1z * is; r.w = a1w * is;
                    ((float4*)out)[(size_t)node1 * 16 + c] = r;
                }
            }
        }
    } else {
        // oversized bucket: scan segment from global (correctness fallback)
        for (int nl = w * 8; nl < w * 8 + 8; ++nl) {
            int node = nbase + nl;
            if (node >= n_nodes) break;
            int deg = lh[nl];
            float ax = 0.f, ay = 0.f, az = 0.f, aw = 0.f;
            int hv = (half << 6) | nl;
            for (int i2 = g; i2 < cnt; i2 += 4) {
                int v = arrA[s + i2];
                if ((v & 127) == hv) {
                    int sa = v >> 7;
                    uint2 va = h2[(size_t)sa * 16 + c];
                    float2 f;
                    uc.u = va.x; f = __half22float2(uc.h); ax += f.x; ay += f.y;
                    uc.u = va.y; f = __half22float2(uc.h); az += f.x; aw += f.y;
                }
            }
            ax += __shfl_xor(ax, 16); ay += __shfl_xor(ay, 16);
            az += __shfl_xor(az, 16); aw += __shfl_xor(aw, 16);
            ax += __shfl_xor(ax, 32); ay += __shfl_xor(ay, 32);
            az += __shfl_xor(az, 32); aw += __shfl_xor(aw, 32);
            if (g == 0) {
                float is = rsqrtf((float)(deg > 1 ? deg : 1));
                float4 r;
                r.x = ax * is; r.y = ay * is; r.z = az * is; r.w = aw * is;
                ((float4*)out)[(size_t)node * 16 + c] = r;
            }
        }
    }
}

// ---------------- fallback: atomic scatter path (tiny ws) ----------------
__global__ void fb_zero(float* __restrict__ out, long long n_out,
                        int* __restrict__ deg, int n_deg) {
    long long i = (long long)blockIdx.x * blockDim.x + threadIdx.x;
    long long stride = (long long)gridDim.x * blockDim.x;
    for (long long j = i; j < n_out; j += stride) out[j] = 0.0f;
    for (long long j = i; j < n_deg; j += stride) deg[j] = 0;
}

__global__ void fb_degree(const int* __restrict__ src, const int* __restrict__ dst,
                          int n_edges, int* __restrict__ outdeg, int* __restrict__ indeg) {
    int i = blockIdx.x * blockDim.x + threadIdx.x;
    int stride = gridDim.x * blockDim.x;
    for (int e = i; e < n_edges; e += stride) {
        atomicAdd(&outdeg[src[e]], 1);
        atomicAdd(&indeg[dst[e]], 1);
    }
}

__global__ void fb_scatter(const float* __restrict__ emb,
                           const int* __restrict__ src, const int* __restrict__ dst,
                           const int* __restrict__ outdeg,
                           float* __restrict__ out, int n_edges) {
    const int epb = blockDim.x >> 6;
    const int d = threadIdx.x & 63;
    long long e0 = (long long)blockIdx.x * epb + (threadIdx.x >> 6);
    long long estride = (long long)gridDim.x * epb;
    for (long long e = e0; e < n_edges; e += estride) {
        int s = src[e];
        int tt = dst[e];
        int od = outdeg[s];
        float v = emb[(long long)s * D_FEAT + d] * rsqrtf((float)(od > 1 ? od : 1));
        atomicAdd(&out[(long long)tt * D_FEAT + d], v);
    }
}

__global__ void fb_scale(float* __restrict__ out, const int* __restrict__ indeg,
                         long long n_elems) {
    long long i = (long long)blockIdx.x * blockDim.x + threadIdx.x;
    long long stride = (long long)gridDim.x * blockDim.x;
    for (long long j = i; j < n_elems; j += stride) {
        int id = indeg[(int)(j >> 6)];
        out[j] *= rsqrtf((float)(id > 1 ? id : 1));
    }
}

extern "C" void kernel_launch(void* const* d_in, const int* in_sizes, int n_in,
                              void* d_out, int out_size, void* d_ws, size_t ws_size,
                              hipStream_t stream) {
    const float* emb = (const float*)d_in[0];
    const int* src = (const int*)d_in[1];
    const int* dst = (const int*)d_in[2];
    const int n_nodes = in_sizes[0] / D_FEAT;
    const int n_edges = in_sizes[1];
    float* out = (float*)d_out;
    const int block = 256;
    const int nb = (n_nodes + NPB - 1) / NPB;
    const int K = NBMAX;

    // layout (ints): oscale | dbcnt8 | sbcnt8 | dbstart | gcursor | sbstart |
    //                scursor | arrA | region{arrS bytes -> h2}
    float* oscale = (float*)d_ws;                    // N
    int* dbcnt8 = (int*)(oscale + n_nodes);          // 8K
    int* sbcnt8 = dbcnt8 + 8 * K;                    // 8K
    int* dbstart = sbcnt8 + 8 * K;                   // K+1
    int* gcursor = dbstart + K + 1;                  // K
    int* sbstart = gcursor + K;                      // K+1
    int* scursor = sbstart + K + 1;                  // K
    int* arrA = scursor + K;                         // E
    int* region = arrA + n_edges;                    // max(E/4, (N+1)*32) ints
    unsigned char* arrS = (unsigned char*)region;    // E bytes (consumed by scount)
    uint2* h2 = (uint2*)region;                      // (N+1)*16 uint2 (after scount)

    size_t region_ints = (size_t)(n_nodes + 1) * 32;
    size_t arrS_ints = ((size_t)n_edges + 3) / 4;
    if (arrS_ints > region_ints) region_ints = arrS_ints;
    size_t need = ((size_t)n_nodes + 16 * (size_t)K + 2 * (size_t)(K + 1) + 2 * (size_t)K
                   + (size_t)n_edges + region_ints) * sizeof(int);

    if (ws_size >= need && nb <= K) {
        zero_ints<<<32, block, 0, stream>>>(dbcnt8, 16 * K);
        bcnt_kernel<<<384, block, 0, stream>>>(src, dst, n_edges, dbcnt8, sbcnt8);
        scan2_kernel<<<2, K, 0, stream>>>(dbcnt8, sbcnt8, dbstart, gcursor,
                                          sbstart, scursor, n_edges);
        int pblocks = (n_edges + CHUNK - 1) / CHUNK;
        dualpart_kernel<<<pblocks, 256, 0, stream>>>(src, dst, n_edges, gcursor,
                                                     scursor, arrA, arrS);
        scount_kernel<<<nb, 256, 0, stream>>>(arrS, sbstart, oscale, n_nodes);
        int n_total = (n_nodes + 1) * 16;
        h_prepass_kernel<<<2048, block, 0, stream>>>((const float4*)emb, oscale,
                                                     h2, n_total, n_nodes);
        sortagg_kernel<<<2 * nb, 512, 0, stream>>>(h2, arrA, dbstart, out, n_nodes);
    } else {
        int* foutdeg = (int*)d_ws;
        int* findeg = foutdeg + n_nodes;
        long long n_out = (long long)n_nodes * D_FEAT;
        fb_zero<<<2048, block, 0, stream>>>(out, n_out, foutdeg, 2 * n_nodes);
        fb_degree<<<2048, block, 0, stream>>>(src, dst, n_edges, foutdeg, findeg);
        fb_scatter<<<2048, block, 0, stream>>>(emb, src, dst, foutdeg, out, n_edges);
        fb_scale<<<2048, block, 0, stream>>>(out, findeg, n_out);
    }
}

// Round 15
// 116.746 us; speedup vs baseline: 1.1564x; 1.1564x over previous
//
#include <hip/hip_runtime.h>
#include <hip/hip_fp16.h>

#define D_FEAT 64
#define NPB 128            // nodes per bucket (node >> 7)
#define NBMAX 1024         // bucket count both sides (pow2)
#define CHUNK 8192         // edges per partition block (arrA run = 8 ints = 32B)
#define EPT 32             // CHUNK / 256
#define CAPB 2816          // full-bucket register staging capacity
#define CAPB_H 1536        // half-bucket srcS capacity (mean 1023 + ~16 sigma)
#define RPT 6              // ceil(CAPB / 512)

// ---------------- zero ----------------
__global__ void zero_ints(int* __restrict__ p, int n) {
    int i = blockIdx.x * blockDim.x + threadIdx.x;
    int stride = gridDim.x * blockDim.x;
    for (int j = i; j < n; j += stride) p[j] = 0;
}

// ---------------- bucket counts for BOTH sides ----------------
__global__ __launch_bounds__(256) void bcnt_kernel(
        const int* __restrict__ src, const int* __restrict__ dst, int n_edges,
        int* __restrict__ dbcnt8, int* __restrict__ sbcnt8) {
    __shared__ int ld[NBMAX];
    __shared__ int ls[NBMAX];
    int t = threadIdx.x;
    for (int i = t; i < NBMAX; i += 256) { ld[i] = 0; ls[i] = 0; }
    __syncthreads();
    int i0 = blockIdx.x * blockDim.x + t;
    int stride = gridDim.x * blockDim.x;
    for (int e = i0; e < n_edges; e += stride) {
        atomicAdd(&ld[dst[e] >> 7], 1);
        atomicAdd(&ls[src[e] >> 7], 1);
    }
    __syncthreads();
    int* dmy = dbcnt8 + (blockIdx.x & 7) * NBMAX;
    int* smy = sbcnt8 + (blockIdx.x & 7) * NBMAX;
    for (int i = t; i < NBMAX; i += 256) {
        if (ld[i]) atomicAdd(&dmy[i], ld[i]);
        if (ls[i]) atomicAdd(&smy[i], ls[i]);
    }
}

// ---------------- dual exclusive scan: block 0 = dst side, block 1 = src side ----
__global__ void scan2_kernel(const int* __restrict__ dbcnt8, const int* __restrict__ sbcnt8,
                             int* __restrict__ dbstart, int* __restrict__ gcursor,
                             int* __restrict__ sbstart, int* __restrict__ scursor,
                             int n_edges) {
    __shared__ int wsum[16];
    int t = threadIdx.x, lane = t & 63, w = t >> 6;
    const int* c8 = (blockIdx.x == 0) ? dbcnt8 : sbcnt8;
    int* bs = (blockIdx.x == 0) ? dbstart : sbstart;
    int* cur = (blockIdx.x == 0) ? gcursor : scursor;
    int v = 0;
    #pragma unroll
    for (int c = 0; c < 8; ++c) v += c8[c * NBMAX + t];
    int inc = v;
    #pragma unroll
    for (int off = 1; off < 64; off <<= 1) {
        int y = __shfl_up(inc, off);
        if (lane >= off) inc += y;
    }
    if (lane == 63) wsum[w] = inc;
    __syncthreads();
    int add = 0;
    #pragma unroll
    for (int i = 0; i < 15; ++i) if (i < w) add += wsum[i];
    int ex = add + inc - v;
    bs[t] = ex;
    cur[t] = ex;
    if (t == NBMAX - 1) bs[NBMAX] = n_edges;
}

// ---------------- fused dual partition (CHUNK=8192, stride-256 bucket mapping) ---
// Phase D: arrA[pk = (src<<7)|(dst&127)] bucketed by dst>>7
// Phase S: arrS[src&127 byte] bucketed by src>>7  (same LDS reused)
__global__ __launch_bounds__(256) void dualpart_kernel(
        const int* __restrict__ src, const int* __restrict__ dst, int n_edges,
        int* __restrict__ gcursor, int* __restrict__ scursor,
        int* __restrict__ arrA, unsigned char* __restrict__ arrS) {
    __shared__ int lhist[NBMAX];
    __shared__ int lstart[NBMAX];
    __shared__ int ldelta[NBMAX];
    __shared__ int lcur[NBMAX];
    __shared__ int part[256];
    __shared__ int pkLDS[CHUNK];
    __shared__ unsigned short bktLDS[CHUNK];

    int t = threadIdx.x;
    long long cbase = (long long)blockIdx.x * CHUNK;
    int cnt = (n_edges - cbase < CHUNK) ? (int)(n_edges - cbase) : CHUNK;

    for (int i = t; i < NBMAX; i += 256) lhist[i] = 0;
    __syncthreads();

    int ssrc[EPT], sdst[EPT];
    #pragma unroll
    for (int i = 0; i < EPT; ++i) {
        long long e = cbase + t + i * 256;
        if (e < n_edges) {
            ssrc[i] = src[e];
            sdst[i] = dst[e];
            atomicAdd(&lhist[sdst[i] >> 7], 1);
        } else {
            ssrc[i] = -1;
            sdst[i] = -1;
        }
    }
    __syncthreads();

    // ---- phase D scan ----
    int b0 = 4 * t;
    int h0 = lhist[b0], h1 = lhist[b0 + 1], h2v = lhist[b0 + 2], h3 = lhist[b0 + 3];
    int tot = h0 + h1 + h2v + h3;
    part[t] = tot;
    __syncthreads();
    for (int off = 1; off < 256; off <<= 1) {
        int x = (t >= off) ? part[t - off] : 0;
        __syncthreads();
        part[t] += x;
        __syncthreads();
    }
    int ex = part[t] - tot;
    lstart[b0] = ex;
    lstart[b0 + 1] = ex + h0;
    lstart[b0 + 2] = ex + h0 + h1;
    lstart[b0 + 3] = ex + h0 + h1 + h2v;
    __syncthreads();
    for (int b = t; b < NBMAX; b += 256) {
        lcur[b] = lstart[b];
        int c = lhist[b];
        if (c > 0) ldelta[b] = atomicAdd(&gcursor[b], c) - lstart[b];
    }
    __syncthreads();
    #pragma unroll
    for (int i = 0; i < EPT; ++i) {
        if (sdst[i] >= 0) {
            int b = sdst[i] >> 7;
            int slot = atomicAdd(&lcur[b], 1);
            pkLDS[slot] = (ssrc[i] << 7) | (sdst[i] & 127);
            bktLDS[slot] = (unsigned short)b;
        }
    }
    __syncthreads();
    for (int j = t; j < cnt; j += 256) {
        int b = bktLDS[j];
        arrA[j + ldelta[b]] = pkLDS[j];
    }
    __syncthreads();

    // ---- phase S (reuse all LDS) ----
    for (int i = t; i < NBMAX; i += 256) lhist[i] = 0;
    __syncthreads();
    #pragma unroll
    for (int i = 0; i < EPT; ++i) {
        if (ssrc[i] >= 0) atomicAdd(&lhist[ssrc[i] >> 7], 1);
    }
    __syncthreads();
    h0 = lhist[b0]; h1 = lhist[b0 + 1]; h2v = lhist[b0 + 2]; h3 = lhist[b0 + 3];
    tot = h0 + h1 + h2v + h3;
    part[t] = tot;
    __syncthreads();
    for (int off = 1; off < 256; off <<= 1) {
        int x = (t >= off) ? part[t - off] : 0;
        __syncthreads();
        part[t] += x;
        __syncthreads();
    }
    ex = part[t] - tot;
    lstart[b0] = ex;
    lstart[b0 + 1] = ex + h0;
    lstart[b0 + 2] = ex + h0 + h1;
    lstart[b0 + 3] = ex + h0 + h1 + h2v;
    __syncthreads();
    for (int b = t; b < NBMAX; b += 256) {
        lcur[b] = lstart[b];
        int c = lhist[b];
        if (c > 0) ldelta[b] = atomicAdd(&scursor[b], c) - lstart[b];
    }
    __syncthreads();
    unsigned char* stg = (unsigned char*)pkLDS;
    #pragma unroll
    for (int i = 0; i < EPT; ++i) {
        if (ssrc[i] >= 0) {
            int b = ssrc[i] >> 7;
            int slot = atomicAdd(&lcur[b], 1);
            stg[slot] = (unsigned char)(ssrc[i] & 127);
            bktLDS[slot] = (unsigned short)b;
        }
    }
    __syncthreads();
    for (int j = t; j < cnt; j += 256) {
        int b = bktLDS[j];
        arrS[j + ldelta[b]] = stg[j];
    }
}

// ---------------- out-degree -> oscale (one block per src bucket, race-free) ------
__global__ __launch_bounds__(256) void scount_kernel(
        const unsigned char* __restrict__ arrS, const int* __restrict__ sbstart,
        float* __restrict__ oscale, int n_nodes) {
    __shared__ int lh[NPB];
    int b = blockIdx.x, t = threadIdx.x;
    int s = sbstart[b], e = sbstart[b + 1];
    if (t < NPB) lh[t] = 0;
    __syncthreads();
    for (int i = s + t; i < e; i += 256) atomicAdd(&lh[arrS[i]], 1);
    __syncthreads();
    if (t < NPB) {
        int node = b * NPB + t;
        if (node < n_nodes) {
            int od = lh[t];
            oscale[node] = rsqrtf((float)(od > 1 ? od : 1));
        }
    }
}

// ---------------- h prepass (grid-stride; h2 overwrites arrS only after scount) ---
__global__ void h_prepass_kernel(const float4* __restrict__ emb4,
                                 const float* __restrict__ oscale,
                                 uint2* __restrict__ h2, int n_total, int n_nodes) {
    int i = blockIdx.x * blockDim.x + threadIdx.x;
    int stride = gridDim.x * blockDim.x;
    for (int j = i; j < n_total; j += stride) {
        int node = j >> 4;
        uint2 r;
        if (node < n_nodes) {
            float s = oscale[node];
            float4 v = emb4[j];
            __half2 a = __floats2half2_rn(v.x * s, v.y * s);
            __half2 b = __floats2half2_rn(v.z * s, v.w * s);
            union { __half2 h; unsigned int u; } ua, ub;
            ua.h = a; ub.h = b;
            r.x = ua.u; r.y = ub.u;
        } else {
            r.x = 0; r.y = 0;
        }
        h2[j] = r;
    }
}

// ---------------- fused sort + aggregate: 2 blocks/bucket, 512 thr, reg staging ---
__global__ __launch_bounds__(512) void sortagg_kernel(
        const uint2* __restrict__ h2, const int* __restrict__ arrA,
        const int* __restrict__ dbstart, float* __restrict__ out, int n_nodes) {
    __shared__ int lh[64];
    __shared__ int lst[64];
    __shared__ int lcur[64];
    __shared__ int srcS[CAPB_H];
    int b = blockIdx.x >> 1, half = blockIdx.x & 1;
    int t = threadIdx.x;
    int s = dbstart[b], e = dbstart[b + 1];
    int cnt = e - s;
    bool fit = (cnt <= CAPB);

    if (t < 64) lh[t] = 0;
    __syncthreads();
    int pkreg[RPT];
    if (fit) {
        #pragma unroll
        for (int i = 0; i < RPT; ++i) {
            int idx = t + i * 512;
            int pk = (idx < cnt) ? arrA[s + idx] : -1;
            pkreg[i] = pk;
            if (pk >= 0 && (((pk >> 6) & 1) == half)) atomicAdd(&lh[pk & 63], 1);
        }
    } else {
        for (int i = t; i < cnt; i += 512) {
            int v = arrA[s + i];
            if (((v >> 6) & 1) == half) atomicAdd(&lh[v & 63], 1);
        }
    }
    __syncthreads();
    if (t < 64) {
        int l0 = lh[t];
        int a = l0;
        #pragma unroll
        for (int off = 1; off < 64; off <<= 1) {
            int y = __shfl_up(a, off);
            if (t >= off) a += y;
        }
        lst[t] = a - l0;
        lcur[t] = a - l0;
    }
    __syncthreads();
    int halfcnt = lst[63] + lh[63];
    bool useS = fit && (halfcnt <= CAPB_H);
    if (useS) {
        #pragma unroll
        for (int i = 0; i < RPT; ++i) {
            int pk = pkreg[i];
            if (pk >= 0 && (((pk >> 6) & 1) == half)) {
                int slot = atomicAdd(&lcur[pk & 63], 1);
                srcS[slot] = pk >> 7;
            }
        }
    }
    __syncthreads();

    int w = t >> 6, L = t & 63, g = L >> 4, c = L & 15;
    int nbase = b * NPB + half * 64;
    union { unsigned int u; __half2 h; } uc;
    for (int nl = w * 8; nl < w * 8 + 8; ++nl) {
        int node = nbase + nl;
        if (node >= n_nodes) break;
        int st = lst[nl];
        int deg = lh[nl];
        int en = st + deg;
        float ax = 0.f, ay = 0.f, az = 0.f, aw = 0.f;
        if (useS) {
            for (int eidx = st; eidx < en; eidx += 16) {
                int ea = eidx + g, eb = ea + 4, ec = ea + 8, ed = ea + 12;
                int sa = (ea < en) ? srcS[ea] : n_nodes;
                int sb = (eb < en) ? srcS[eb] : n_nodes;
                int sc = (ec < en) ? srcS[ec] : n_nodes;
                int sd = (ed < en) ? srcS[ed] : n_nodes;
                uint2 va = h2[(size_t)sa * 16 + c];
                uint2 vb = h2[(size_t)sb * 16 + c];
                uint2 vc = h2[(size_t)sc * 16 + c];
                uint2 vd = h2[(size_t)sd * 16 + c];
                float2 f;
                uc.u = va.x; f = __half22float2(uc.h); ax += f.x; ay += f.y;
                uc.u = va.y; f = __half22float2(uc.h); az += f.x; aw += f.y;
                uc.u = vb.x; f = __half22float2(uc.h); ax += f.x; ay += f.y;
                uc.u = vb.y; f = __half22float2(uc.h); az += f.x; aw += f.y;
                uc.u = vc.x; f = __half22float2(uc.h); ax += f.x; ay += f.y;
                uc.u = vc.y; f = __half22float2(uc.h); az += f.x; aw += f.y;
                uc.u = vd.x; f = __half22float2(uc.h); ax += f.x; ay += f.y;
                uc.u = vd.y; f = __half22float2(uc.h); az += f.x; aw += f.y;
            }
        } else {
            int hv = (half << 6) | nl;
            for (int i2 = g; i2 < cnt; i2 += 4) {
                int v = arrA[s + i2];
                if ((v & 127) == hv) {
                    int sa = v >> 7;
                    uint2 va = h2[(size_t)sa * 16 + c];
                    float2 f;
                    uc.u = va.x; f = __half22float2(uc.h); ax += f.x; ay += f.y;
                    uc.u = va.y; f = __half22float2(uc.h); az += f.x; aw += f.y;
                }
            }
        }
        ax += __shfl_xor(ax, 16); ay += __shfl_xor(ay, 16);
        az += __shfl_xor(az, 16); aw += __shfl_xor(aw, 16);
        ax += __shfl_xor(ax, 32); ay += __shfl_xor(ay, 32);
        az += __shfl_xor(az, 32); aw += __shfl_xor(aw, 32);
        if (g == 0) {
            float is = rsqrtf((float)(deg > 1 ? deg : 1));
            float4 r;
            r.x = ax * is; r.y = ay * is; r.z = az * is; r.w = aw * is;
            ((float4*)out)[(size_t)node * 16 + c] = r;
        }
    }
}

// ---------------- fallback: atomic scatter path (tiny ws) ----------------
__global__ void fb_zero(float* __restrict__ out, long long n_out,
                        int* __restrict__ deg, int n_deg) {
    long long i = (long long)blockIdx.x * blockDim.x + threadIdx.x;
    long long stride = (long long)gridDim.x * blockDim.x;
    for (long long j = i; j < n_out; j += stride) out[j] = 0.0f;
    for (long long j = i; j < n_deg; j += stride) deg[j] = 0;
}

__global__ void fb_degree(const int* __restrict__ src, const int* __restrict__ dst,
                          int n_edges, int* __restrict__ outdeg, int* __restrict__ indeg) {
    int i = blockIdx.x * blockDim.x + threadIdx.x;
    int stride = gridDim.x * blockDim.x;
    for (int e = i; e < n_edges; e += stride) {
        atomicAdd(&outdeg[src[e]], 1);
        atomicAdd(&indeg[dst[e]], 1);
    }
}

__global__ void fb_scatter(const float* __restrict__ emb,
                           const int* __restrict__ src, const int* __restrict__ dst,
                           const int* __restrict__ outdeg,
                           float* __restrict__ out, int n_edges) {
    const int epb = blockDim.x >> 6;
    const int d = threadIdx.x & 63;
    long long e0 = (long long)blockIdx.x * epb + (threadIdx.x >> 6);
    long long estride = (long long)gridDim.x * epb;
    for (long long e = e0; e < n_edges; e += estride) {
        int s = src[e];
        int tt = dst[e];
        int od = outdeg[s];
        float v = emb[(long long)s * D_FEAT + d] * rsqrtf((float)(od > 1 ? od : 1));
        atomicAdd(&out[(long long)tt * D_FEAT + d], v);
    }
}

__global__ void fb_scale(float* __restrict__ out, const int* __restrict__ indeg,
                         long long n_elems) {
    long long i = (long long)blockIdx.x * blockDim.x + threadIdx.x;
    long long stride = (long long)gridDim.x * blockDim.x;
    for (long long j = i; j < n_elems; j += stride) {
        int id = indeg[(int)(j >> 6)];
        out[j] *= rsqrtf((float)(id > 1 ? id : 1));
    }
}

extern "C" void kernel_launch(void* const* d_in, const int* in_sizes, int n_in,
                              void* d_out, int out_size, void* d_ws, size_t ws_size,
                              hipStream_t stream) {
    const float* emb = (const float*)d_in[0];
    const int* src = (const int*)d_in[1];
    const int* dst = (const int*)d_in[2];
    const int n_nodes = in_sizes[0] / D_FEAT;
    const int n_edges = in_sizes[1];
    float* out = (float*)d_out;
    const int block = 256;
    const int nb = (n_nodes + NPB - 1) / NPB;
    const int K = NBMAX;

    // layout (ints): oscale | dbcnt8 | sbcnt8 | dbstart | gcursor | sbstart |
    //                scursor | arrA | region{arrS bytes -> h2}
    float* oscale = (float*)d_ws;                    // N
    int* dbcnt8 = (int*)(oscale + n_nodes);          // 8K
    int* sbcnt8 = dbcnt8 + 8 * K;                    // 8K
    int* dbstart = sbcnt8 + 8 * K;                   // K+1
    int* gcursor = dbstart + K + 1;                  // K
    int* sbstart = gcursor + K;                      // K+1
    int* scursor = sbstart + K + 1;                  // K
    int* arrA = scursor + K;                         // E
    int* region = arrA + n_edges;                    // max(E/4, (N+1)*32) ints
    unsigned char* arrS = (unsigned char*)region;    // E bytes (consumed by scount)
    uint2* h2 = (uint2*)region;                      // (N+1)*16 uint2 (after scount)

    size_t region_ints = (size_t)(n_nodes + 1) * 32;
    size_t arrS_ints = ((size_t)n_edges + 3) / 4;
    if (arrS_ints > region_ints) region_ints = arrS_ints;
    size_t need = ((size_t)n_nodes + 16 * (size_t)K + 2 * (size_t)(K + 1) + 2 * (size_t)K
                   + (size_t)n_edges + region_ints) * sizeof(int);

    if (ws_size >= need && nb <= K) {
        zero_ints<<<32, block, 0, stream>>>(dbcnt8, 16 * K);
        bcnt_kernel<<<384, block, 0, stream>>>(src, dst, n_edges, dbcnt8, sbcnt8);
        scan2_kernel<<<2, K, 0, stream>>>(dbcnt8, sbcnt8, dbstart, gcursor,
                                          sbstart, scursor, n_edges);
        int pblocks = (n_edges + CHUNK - 1) / CHUNK;
        dualpart_kernel<<<pblocks, 256, 0, stream>>>(src, dst, n_edges, gcursor,
                                                     scursor, arrA, arrS);
        scount_kernel<<<nb, 256, 0, stream>>>(arrS, sbstart, oscale, n_nodes);
        int n_total = (n_nodes + 1) * 16;
        h_prepass_kernel<<<2048, block, 0, stream>>>((const float4*)emb, oscale,
                                                     h2, n_total, n_nodes);
        sortagg_kernel<<<2 * nb, 512, 0, stream>>>(h2, arrA, dbstart, out, n_nodes);
    } else {
        int* foutdeg = (int*)d_ws;
        int* findeg = foutdeg + n_nodes;
        long long n_out = (long long)n_nodes * D_FEAT;
        fb_zero<<<2048, block, 0, stream>>>(out, n_out, foutdeg, 2 * n_nodes);
        fb_degree<<<2048, block, 0, stream>>>(src, dst, n_edges, foutdeg, findeg);
        fb_scatter<<<2048, block, 0, stream>>>(emb, src, dst, foutdeg, out, n_edges);
        fb_scale<<<2048, block, 0, stream>>>(out, findeg, n_out);
    }
}